// Round 6
// baseline (119.019 us; speedup 1.0000x reference)
//
#include <hip/hip_runtime.h>
#include <math.h>

// riemannian_exp: out[b] = key_poses[argmax(ybin[b])] @ Rodrigues(yres[b])
// B = 1048576, C = 100.
// Round 6: DRAM page-locality experiment. 512 persistent blocks (2048 waves);
// each wave walks a contiguous row span page-major: 16 lanes/row -> one
// wave-instruction touches a contiguous 1.6 KB window (~1 DRAM page),
// depth-2 prefetch. Rodrigues+store per 256-row supertile, fully parallel.

typedef float fvec4 __attribute__((ext_vector_type(4)));

#define NBLOCKS 512
#define SUPER   256   // rows per supertile per block

__global__ __launch_bounds__(256) void rexp_pm_kernel(
    const float* __restrict__ ybin,      // [B, 100]
    const float* __restrict__ yres,      // [B, 3]
    const float* __restrict__ key_poses, // [100, 3, 3]
    float* __restrict__ out,             // [B, 3, 3]
    int B)
{
    __shared__ float s_kp[900];
    __shared__ int   s_bi[SUPER];
    __shared__ float s_yres[SUPER * 3];
    __shared__ float s_out[SUPER * 9];

    const int tid   = threadIdx.x;
    const int wave  = tid >> 6;      // 0..3
    const int lane  = tid & 63;
    const int lane16 = lane & 15;
    const int rquad  = lane >> 4;    // 0..3

    for (int i = tid; i < 900; i += 256) s_kp[i] = key_poses[i];

    const int rows_per_block = B / NBLOCKS;        // 2048
    const int n_super = rows_per_block / SUPER;    // 8
    const long long blk_row0 = (long long)blockIdx.x * rows_per_block;
    const fvec4* gy = reinterpret_cast<const fvec4*>(ybin);

    for (int st = 0; st < n_super; ++st) {
        const long long tile_row0 = blk_row0 + (long long)st * SUPER;

        // stage yres for this supertile: 768 floats = 192 fvec4, coalesced
        if (tid < 192)
            reinterpret_cast<fvec4*>(s_yres)[tid] =
                reinterpret_cast<const fvec4*>(yres + tile_row0 * 3)[tid];

        // ---- phase 1: argmax. wave w owns rows [tile_row0+w*64, +64),
        //      16 passes x 4 rows; per pass one contiguous 1.6 KB window ----
        const long long wrow0 = tile_row0 + wave * 64;

        // prefetch pass 0
        long long rbase = (wrow0 + rquad) * 25;
        fvec4 c0 = gy[rbase + lane16];
        fvec4 c1 = (lane16 < 9) ? gy[rbase + 16 + lane16] : c0;

        for (int p = 0; p < 16; ++p) {
            fvec4 n0 = c0, n1 = c1;
            if (p + 1 < 16) {
                long long nb = (wrow0 + (p + 1) * 4 + rquad) * 25;
                n0 = gy[nb + lane16];
                if (lane16 < 9) n1 = gy[nb + 16 + lane16];
            }

            // per-lane argmax over its 4 (+4) elements
            int i0 = lane16 * 4;
            float best = c0.x; int bi = i0;
            if (c0.y > best) { best = c0.y; bi = i0 + 1; }
            if (c0.z > best) { best = c0.z; bi = i0 + 2; }
            if (c0.w > best) { best = c0.w; bi = i0 + 3; }
            if (lane16 < 9) {
                int i1 = 64 + lane16 * 4;
                if (c1.x > best) { best = c1.x; bi = i1;     }
                if (c1.y > best) { best = c1.y; bi = i1 + 1; }
                if (c1.z > best) { best = c1.z; bi = i1 + 2; }
                if (c1.w > best) { best = c1.w; bi = i1 + 3; }
            }
            // reduce over the 16-lane group, first-index tiebreak
            #pragma unroll
            for (int m = 1; m <= 8; m <<= 1) {
                float ob = __shfl_xor(best, m);
                int   oi = __shfl_xor(bi, m);
                if (ob > best || (ob == best && oi < bi)) { best = ob; bi = oi; }
            }
            if (lane16 == 0) s_bi[wave * 64 + p * 4 + rquad] = bi;

            c0 = n0; c1 = n1;
        }
        __syncthreads();

        // ---- phase 2: Rodrigues + matmul, 1 row per thread ----
        {
            int bi = s_bi[tid];
            float rx = s_yres[tid * 3 + 0];
            float ry = s_yres[tid * 3 + 1];
            float rz = s_yres[tid * 3 + 2];
            float angle = sqrtf(rx * rx + ry * ry + rz * rz);
            float inv = 1.0f / fmaxf(angle, 1e-12f);
            float ax = rx * inv, ay = ry * inv, az = rz * inv;
            float s, cosv;
            __sincosf(angle, &s, &cosv);
            float c = 1.0f - cosv;

            float axx = ax * ax, ayy = ay * ay, azz = az * az;
            float axy = ax * ay, axz = ax * az, ayz = ay * az;

            float R00 = 1.0f + c * (-ayy - azz);
            float R01 = -s * az + c * axy;
            float R02 =  s * ay + c * axz;
            float R10 =  s * az + c * axy;
            float R11 = 1.0f + c * (-axx - azz);
            float R12 = -s * ax + c * ayz;
            float R20 = -s * ay + c * axz;
            float R21 =  s * ax + c * ayz;
            float R22 = 1.0f + c * (-axx - ayy);

            const float* P = &s_kp[bi * 9];
            float P00 = P[0], P01 = P[1], P02 = P[2];
            float P10 = P[3], P11 = P[4], P12 = P[5];
            float P20 = P[6], P21 = P[7], P22 = P[8];

            float* o = &s_out[tid * 9];
            o[0] = P00 * R00 + P01 * R10 + P02 * R20;
            o[1] = P00 * R01 + P01 * R11 + P02 * R21;
            o[2] = P00 * R02 + P01 * R12 + P02 * R22;
            o[3] = P10 * R00 + P11 * R10 + P12 * R20;
            o[4] = P10 * R01 + P11 * R11 + P12 * R21;
            o[5] = P10 * R02 + P11 * R12 + P12 * R22;
            o[6] = P20 * R00 + P21 * R10 + P22 * R20;
            o[7] = P20 * R01 + P21 * R11 + P22 * R21;
            o[8] = P20 * R02 + P21 * R12 + P22 * R22;
        }
        __syncthreads();

        // ---- coalesced store: 2304 floats = 576 fvec4 ----
        {
            fvec4* dst = reinterpret_cast<fvec4*>(out + tile_row0 * 9);
            const fvec4* src = reinterpret_cast<const fvec4*>(s_out);
            dst[tid]       = src[tid];
            dst[tid + 256] = src[tid + 256];
            if (tid < 64) dst[tid + 512] = src[tid + 512];
        }
        __syncthreads();  // s_bi/s_yres/s_out reused next supertile
    }
}

// ---------------- Fallback: fused single kernel (generic) ----------------
__global__ void rexp_generic_kernel(
    const float* __restrict__ ybin, const float* __restrict__ yres,
    const float* __restrict__ key_poses, float* __restrict__ out,
    int B, int C)
{
    long long b = (long long)blockIdx.x * blockDim.x + threadIdx.x;
    if (b >= B) return;
    const float* row = ybin + b * C;
    float best = -INFINITY; int bi = 0;
    for (int j = 0; j < C; ++j) if (row[j] > best) { best = row[j]; bi = j; }
    float rx = yres[b*3], ry = yres[b*3+1], rz = yres[b*3+2];
    float angle = sqrtf(rx*rx + ry*ry + rz*rz);
    float inv = 1.0f / fmaxf(angle, 1e-12f);
    float ax = rx*inv, ay = ry*inv, az = rz*inv;
    float s, cosv; __sincosf(angle, &s, &cosv);
    float c = 1.0f - cosv;
    float axx=ax*ax, ayy=ay*ay, azz=az*az, axy=ax*ay, axz=ax*az, ayz=ay*az;
    float R00=1.0f+c*(-ayy-azz), R01=-s*az+c*axy, R02= s*ay+c*axz;
    float R10= s*az+c*axy, R11=1.0f+c*(-axx-azz), R12=-s*ax+c*ayz;
    float R20=-s*ay+c*axz, R21= s*ax+c*ayz, R22=1.0f+c*(-axx-ayy);
    const float* P = key_poses + bi * 9;
    float* o = out + b * 9;
    o[0]=P[0]*R00+P[1]*R10+P[2]*R20; o[1]=P[0]*R01+P[1]*R11+P[2]*R21; o[2]=P[0]*R02+P[1]*R12+P[2]*R22;
    o[3]=P[3]*R00+P[4]*R10+P[5]*R20; o[4]=P[3]*R01+P[4]*R11+P[5]*R21; o[5]=P[3]*R02+P[4]*R12+P[5]*R22;
    o[6]=P[6]*R00+P[7]*R10+P[8]*R20; o[7]=P[6]*R01+P[7]*R11+P[8]*R21; o[8]=P[6]*R02+P[7]*R12+P[8]*R22;
}

extern "C" void kernel_launch(void* const* d_in, const int* in_sizes, int n_in,
                              void* d_out, int out_size, void* d_ws, size_t ws_size,
                              hipStream_t stream) {
    const float* ybin      = (const float*)d_in[0];
    const float* yres      = (const float*)d_in[1];
    const float* key_poses = (const float*)d_in[2];
    float* out = (float*)d_out;

    int B = in_sizes[1] / 3;
    int C = in_sizes[0] / B;   // == 100 here

    if (C == 100 && B % (NBLOCKS * SUPER) == 0) {
        rexp_pm_kernel<<<NBLOCKS, 256, 0, stream>>>(ybin, yres, key_poses, out, B);
    } else {
        rexp_generic_kernel<<<(B + 255) / 256, 256, 0, stream>>>(
            ybin, yres, key_poses, out, B, C);
    }
}

// Round 7
// 95.813 us; speedup vs baseline: 1.2422x; 1.2422x over previous
//
#include <hip/hip_runtime.h>
#include <math.h>

// riemannian_exp: out[b] = key_poses[argmax(ybin[b])] @ Rodrigues(yres[b])
// B = 1048576, C = 100 (hard assumption C==100 in fast path).
// FINAL: revert to the best measured structure (Round 2, 95.9 us).
// Memory-bound on the ybin read (419 MB); effective read BW pins at ~4.9 TB/s
// across 6 structurally distinct implementations -> empirical ceiling.

#define ROWS_PER_BLOCK 256

__global__ __launch_bounds__(256) void rexp_fast_kernel(
    const float* __restrict__ ybin,      // [B, 100]
    const float* __restrict__ yres,      // [B, 3]
    const float* __restrict__ key_poses, // [100, 3, 3]
    float* __restrict__ out)             // [B, 3, 3]
{
    __shared__ float kp[912];      // 100*9 key poses
    __shared__ int   s_bi[256];    // argmax index per row
    __shared__ float s_yres[768];  // 256*3 staged residuals
    __shared__ float s_out[2304];  // 256*9 staged outputs

    const int tid = threadIdx.x;
    const long long row0 = (long long)blockIdx.x * ROWS_PER_BLOCK;

    // stage key_poses (3.6 KB, coalesced)
    for (int i = tid; i < 900; i += 256) kp[i] = key_poses[i];

    // stage yres coalesced: 768 floats = 192 float4
    {
        const float4* src = reinterpret_cast<const float4*>(yres + row0 * 3);
        float4* dst = reinterpret_cast<float4*>(s_yres);
        if (tid < 192) dst[tid] = src[tid];
    }

    // ---- phase 1: cooperative argmax, 4 lanes per row ----
    const int lane4 = tid & 3;
    const int rloc  = tid >> 2;   // 0..63
    #pragma unroll 1
    for (int t = 0; t < 4; ++t) {
        const long long row = row0 + t * 64 + rloc;
        const float4* rbase = reinterpret_cast<const float4*>(ybin + row * 100);
        float best = -INFINITY;
        int bi = 0;
        #pragma unroll
        for (int j = 0; j < 7; ++j) {
            int c = lane4 + j * 4;          // float4 chunk index within row
            if (c < 25) {
                float4 v = rbase[c];        // groups of 4 lanes cover 64B contiguous
                int i0 = c * 4;
                if (v.x > best) { best = v.x; bi = i0;     }
                if (v.y > best) { best = v.y; bi = i0 + 1; }
                if (v.z > best) { best = v.z; bi = i0 + 2; }
                if (v.w > best) { best = v.w; bi = i0 + 3; }
            }
        }
        // reduce (max, first index) across the 4-lane group
        #pragma unroll
        for (int m = 1; m <= 2; m <<= 1) {
            float ob = __shfl_xor(best, m);
            int   oi = __shfl_xor(bi, m);
            if (ob > best || (ob == best && oi < bi)) { best = ob; bi = oi; }
        }
        if (lane4 == 0) s_bi[t * 64 + rloc] = bi;
    }
    __syncthreads();

    // ---- phase 2: one thread per row, all from LDS ----
    {
        int bi = s_bi[tid];
        float rx = s_yres[tid * 3 + 0];
        float ry = s_yres[tid * 3 + 1];
        float rz = s_yres[tid * 3 + 2];
        float angle = sqrtf(rx * rx + ry * ry + rz * rz);
        float inv = 1.0f / fmaxf(angle, 1e-12f);
        float ax = rx * inv, ay = ry * inv, az = rz * inv;
        float s, cosv;
        sincosf(angle, &s, &cosv);
        float c = 1.0f - cosv;

        float axx = ax * ax, ayy = ay * ay, azz = az * az;
        float axy = ax * ay, axz = ax * az, ayz = ay * az;

        float R00 = 1.0f + c * (-ayy - azz);
        float R01 = -s * az + c * axy;
        float R02 =  s * ay + c * axz;
        float R10 =  s * az + c * axy;
        float R11 = 1.0f + c * (-axx - azz);
        float R12 = -s * ax + c * ayz;
        float R20 = -s * ay + c * axz;
        float R21 =  s * ax + c * ayz;
        float R22 = 1.0f + c * (-axx - ayy);

        const float* P = &kp[bi * 9];
        float P00 = P[0], P01 = P[1], P02 = P[2];
        float P10 = P[3], P11 = P[4], P12 = P[5];
        float P20 = P[6], P21 = P[7], P22 = P[8];

        float* o = &s_out[tid * 9];
        o[0] = P00 * R00 + P01 * R10 + P02 * R20;
        o[1] = P00 * R01 + P01 * R11 + P02 * R21;
        o[2] = P00 * R02 + P01 * R12 + P02 * R22;
        o[3] = P10 * R00 + P11 * R10 + P12 * R20;
        o[4] = P10 * R01 + P11 * R11 + P12 * R21;
        o[5] = P10 * R02 + P11 * R12 + P12 * R22;
        o[6] = P20 * R00 + P21 * R10 + P22 * R20;
        o[7] = P20 * R01 + P21 * R11 + P22 * R21;
        o[8] = P20 * R02 + P21 * R12 + P22 * R22;
    }
    __syncthreads();

    // ---- coalesced store: 2304 floats = 576 float4 ----
    {
        float4* dst = reinterpret_cast<float4*>(out + row0 * 9);
        const float4* src = reinterpret_cast<const float4*>(s_out);
        dst[tid]       = src[tid];
        dst[tid + 256] = src[tid + 256];
        if (tid < 64) dst[tid + 512] = src[tid + 512];
    }
}

// Tail kernel for B % 256 rows (not used when B == 1048576, but kept general).
__global__ void rexp_tail_kernel(
    const float* __restrict__ ybin, const float* __restrict__ yres,
    const float* __restrict__ key_poses, float* __restrict__ out,
    int B, int C, int start)
{
    int b = start + blockIdx.x * blockDim.x + threadIdx.x;
    if (b >= B) return;
    const float* row = ybin + (size_t)b * C;
    float best = -INFINITY; int bi = 0;
    for (int j = 0; j < C; ++j) if (row[j] > best) { best = row[j]; bi = j; }
    float rx = yres[(size_t)b*3], ry = yres[(size_t)b*3+1], rz = yres[(size_t)b*3+2];
    float angle = sqrtf(rx*rx + ry*ry + rz*rz);
    float inv = 1.0f / fmaxf(angle, 1e-12f);
    float ax = rx*inv, ay = ry*inv, az = rz*inv;
    float s, cosv; sincosf(angle, &s, &cosv);
    float c = 1.0f - cosv;
    float axx=ax*ax, ayy=ay*ay, azz=az*az, axy=ax*ay, axz=ax*az, ayz=ay*az;
    float R00=1.0f+c*(-ayy-azz), R01=-s*az+c*axy, R02= s*ay+c*axz;
    float R10= s*az+c*axy, R11=1.0f+c*(-axx-azz), R12=-s*ax+c*ayz;
    float R20=-s*ay+c*axz, R21= s*ax+c*ayz, R22=1.0f+c*(-axx-ayy);
    const float* P = key_poses + bi * 9;
    float* o = out + (size_t)b * 9;
    o[0]=P[0]*R00+P[1]*R10+P[2]*R20; o[1]=P[0]*R01+P[1]*R11+P[2]*R21; o[2]=P[0]*R02+P[1]*R12+P[2]*R22;
    o[3]=P[3]*R00+P[4]*R10+P[5]*R20; o[4]=P[3]*R01+P[4]*R11+P[5]*R21; o[5]=P[3]*R02+P[4]*R12+P[5]*R22;
    o[6]=P[6]*R00+P[7]*R10+P[8]*R20; o[7]=P[6]*R01+P[7]*R11+P[8]*R21; o[8]=P[6]*R02+P[7]*R12+P[8]*R22;
}

extern "C" void kernel_launch(void* const* d_in, const int* in_sizes, int n_in,
                              void* d_out, int out_size, void* d_ws, size_t ws_size,
                              hipStream_t stream) {
    const float* ybin      = (const float*)d_in[0];
    const float* yres      = (const float*)d_in[1];
    const float* key_poses = (const float*)d_in[2];
    float* out = (float*)d_out;

    int B = in_sizes[1] / 3;
    int C = in_sizes[0] / B;   // == 100 for this problem

    if (C == 100) {
        int fullBlocks = B / ROWS_PER_BLOCK;
        if (fullBlocks > 0)
            rexp_fast_kernel<<<fullBlocks, 256, 0, stream>>>(ybin, yres, key_poses, out);
        int rem = B - fullBlocks * ROWS_PER_BLOCK;
        if (rem > 0) {
            int start = fullBlocks * ROWS_PER_BLOCK;
            rexp_tail_kernel<<<(rem + 255) / 256, 256, 0, stream>>>(
                ybin, yres, key_poses, out, B, C, start);
        }
    } else {
        rexp_tail_kernel<<<(B + 255) / 256, 256, 0, stream>>>(
            ybin, yres, key_poses, out, B, C, 0);
    }
}